// Round 1
// baseline (754.957 us; speedup 1.0000x reference)
//
#include <hip/hip_runtime.h>
#include <hip/hip_bf16.h>

#define NN 50000
#define NE 800000
#define NG 512
#define HD 128
#define ED 64
#define GD 64
#define HID 128

typedef __attribute__((ext_vector_type(8))) short short8;
typedef __attribute__((ext_vector_type(4))) float f32x4;

__device__ __forceinline__ short f2bf(float f) {
  union { float f; unsigned u; } v; v.f = f;
  unsigned r = v.u + 0x7fffu + ((v.u >> 16) & 1u);
  return (short)(r >> 16);
}

__device__ __forceinline__ short8 load_a8(const float* p) {
  const f32x4* q = (const f32x4*)p;
  f32x4 x0 = q[0], x1 = q[1];
  short8 r;
  r[0]=f2bf(x0[0]); r[1]=f2bf(x0[1]); r[2]=f2bf(x0[2]); r[3]=f2bf(x0[3]);
  r[4]=f2bf(x1[0]); r[5]=f2bf(x1[1]); r[6]=f2bf(x1[2]); r[7]=f2bf(x1[3]);
  return r;
}

// swizzled LDS index (in shorts). rowBytes = row stride in bytes.
__device__ __forceinline__ int swz(int row, int col, int rowBytes) {
  int b = row * rowBytes + col * 2;
  b ^= (row & 7) << 4;
  return b >> 1;
}

// Pack f32 weight W[K][Ncol] -> bf16 Wp[(k>>3)*Ncol*8 + n*8 + (k&7)]
// so a lane's B-fragment (8 consecutive k for one n) is one 16B load.
__global__ void pack_kernel(const float* __restrict__ Wm1, const float* __restrict__ Wm2,
                            const float* __restrict__ We1, const float* __restrict__ We2,
                            const float* __restrict__ Wh1, const float* __restrict__ Wh2,
                            short* __restrict__ out) {
  int gid = blockIdx.x * 256 + threadIdx.x;
  if (gid >= 135168) return;
  const float* W; int Ncol, base, idx;
  if (gid < 49152)       { W = Wm1; Ncol = 128; base = 0;      idx = gid; }
  else if (gid < 65536)  { W = Wm2; Ncol = 128; base = 49152;  idx = gid - 49152; }
  else if (gid < 73728)  { W = We1; Ncol = 64;  base = 65536;  idx = gid - 65536; }
  else if (gid < 77824)  { W = We2; Ncol = 64;  base = 73728;  idx = gid - 73728; }
  else if (gid < 118784) { W = Wh1; Ncol = 128; base = 77824;  idx = gid - 77824; }
  else                   { W = Wh2; Ncol = 128; base = 118784; idx = gid - 118784; }
  int k = idx / Ncol, n = idx % Ncol;
  out[base + (k >> 3) * Ncol * 8 + n * 8 + (k & 7)] = f2bf(W[idx]);
}

// Edge kernel: 64 edges/block, 4 waves x 16 rows.
// m = relu(relu([h_src,h_dst,e,g_eb] @ Wm1 + bm1) @ Wm2 + bm2)
// m_att = sigmoid(m @ Wma + bma); atomicAdd m_aggr[dst] += m_att*m
// e_out = relu(e + relu(m @ We1 + be1) @ We2 + be2)
__global__ __launch_bounds__(256) void edge_kernel(
    const float* __restrict__ h, const int* __restrict__ ei,
    const float* __restrict__ e, const float* __restrict__ g,
    const int* __restrict__ batch,
    const short* __restrict__ pWm1, const float* __restrict__ bm1,
    const short* __restrict__ pWm2, const float* __restrict__ bm2,
    const float* __restrict__ Wma, const float* __restrict__ bma,
    const short* __restrict__ pWe1, const float* __restrict__ be1,
    const short* __restrict__ pWe2, const float* __restrict__ be2,
    float* __restrict__ e_out, float* __restrict__ m_aggr) {
  __shared__ short lds_m[4][16 * 128];
  __shared__ short lds_t[4][16 * 64];

  const int wave = threadIdx.x >> 6;
  const int lane = threadIdx.x & 63;
  const int row16 = lane & 15;
  const int quad = lane >> 4;
  const int ebase = blockIdx.x * 64 + wave * 16;

  const int eidA = ebase + row16;
  const int srcA = ei[eidA];
  const int dstA = ei[NE + eidA];
  const int gbA = batch[dstA];

  const float* seg0 = h + (size_t)srcA * HD;
  const float* seg1 = h + (size_t)dstA * HD;
  const float* seg2 = e + (size_t)eidA * ED;
  const float* seg3 = g + (size_t)gbA * GD;

  // ---- layer m1: [16,384] @ [384,128]
  f32x4 acc[8];
#pragma unroll
  for (int t = 0; t < 8; ++t) acc[t] = (f32x4)0.0f;
#pragma unroll
  for (int c = 0; c < 12; ++c) {
    const float* src; int off;
    if (c < 4)       { src = seg0; off = c * 32; }
    else if (c < 8)  { src = seg1; off = (c - 4) * 32; }
    else if (c < 10) { src = seg2; off = (c - 8) * 32; }
    else             { src = seg3; off = (c - 10) * 32; }
    short8 a = load_a8(src + off + quad * 8);
    const short* bp = pWm1 + (size_t)(c * 4 + quad) * HID * 8 + row16 * 8;
#pragma unroll
    for (int t = 0; t < 8; ++t) {
      short8 b = *(const short8*)(bp + t * 16 * 8);
      acc[t] = __builtin_amdgcn_mfma_f32_16x16x32_bf16(a, b, acc[t], 0, 0, 0);
    }
  }
  // bias+relu -> LDS (bf16, swizzled). D layout: row=quad*4+r, col=t*16+row16
#pragma unroll
  for (int t = 0; t < 8; ++t) {
    float b1 = bm1[t * 16 + row16];
#pragma unroll
    for (int r = 0; r < 4; ++r) {
      float y = fmaxf(acc[t][r] + b1, 0.f);
      lds_m[wave][swz(quad * 4 + r, t * 16 + row16, 256)] = f2bf(y);
    }
  }
  __syncthreads();

  // ---- layer m2: [16,128] @ [128,128]
  f32x4 acc2[8];
#pragma unroll
  for (int t = 0; t < 8; ++t) acc2[t] = (f32x4)0.0f;
#pragma unroll
  for (int c = 0; c < 4; ++c) {
    short8 a = *(const short8*)&lds_m[wave][swz(row16, c * 32 + quad * 8, 256)];
    const short* bp = pWm2 + 49152 * 0 + (size_t)(c * 4 + quad) * HID * 8 + row16 * 8;
#pragma unroll
    for (int t = 0; t < 8; ++t) {
      short8 b = *(const short8*)(bp + t * 16 * 8);
      acc2[t] = __builtin_amdgcn_mfma_f32_16x16x32_bf16(a, b, acc2[t], 0, 0, 0);
    }
  }
  __syncthreads();
  // m = relu(acc2+bm2); keep in regs and store bf16 to LDS
  float mval[8][4];
#pragma unroll
  for (int t = 0; t < 8; ++t) {
    float b2 = bm2[t * 16 + row16];
#pragma unroll
    for (int r = 0; r < 4; ++r) {
      float y = fmaxf(acc2[t][r] + b2, 0.f);
      mval[t][r] = y;
      lds_m[wave][swz(quad * 4 + r, t * 16 + row16, 256)] = f2bf(y);
    }
  }
  __syncthreads();

  // ---- m_att = sigmoid(m . Wma + bma)  (row-dot, reduce 16 lanes)
  float part[4] = {0.f, 0.f, 0.f, 0.f};
#pragma unroll
  for (int t = 0; t < 8; ++t) {
    float w = Wma[t * 16 + row16];
#pragma unroll
    for (int r = 0; r < 4; ++r) part[r] += mval[t][r] * w;
  }
#pragma unroll
  for (int s = 1; s < 16; s <<= 1) {
#pragma unroll
    for (int r = 0; r < 4; ++r) part[r] += __shfl_xor(part[r], s, 64);
  }
  float bma0 = bma[0];
  float attv[4];
#pragma unroll
  for (int r = 0; r < 4; ++r) attv[r] = 1.f / (1.f + __expf(-(part[r] + bma0)));

  // ---- aggregate: m_aggr[dst] += att*m
  int dstS[4];
#pragma unroll
  for (int r = 0; r < 4; ++r) dstS[r] = ei[NE + ebase + quad * 4 + r];
#pragma unroll
  for (int t = 0; t < 8; ++t)
#pragma unroll
    for (int r = 0; r < 4; ++r)
      atomicAdd(&m_aggr[(size_t)dstS[r] * HID + t * 16 + row16], attv[r] * mval[t][r]);

  // ---- layer e1: [16,128] @ [128,64]
  f32x4 acc3[4];
#pragma unroll
  for (int t = 0; t < 4; ++t) acc3[t] = (f32x4)0.0f;
#pragma unroll
  for (int c = 0; c < 4; ++c) {
    short8 a = *(const short8*)&lds_m[wave][swz(row16, c * 32 + quad * 8, 256)];
    const short* bp = pWe1 + (size_t)(c * 4 + quad) * ED * 8 + row16 * 8;
#pragma unroll
    for (int t = 0; t < 4; ++t) {
      short8 b = *(const short8*)(bp + t * 16 * 8);
      acc3[t] = __builtin_amdgcn_mfma_f32_16x16x32_bf16(a, b, acc3[t], 0, 0, 0);
    }
  }
#pragma unroll
  for (int t = 0; t < 4; ++t) {
    float b1 = be1[t * 16 + row16];
#pragma unroll
    for (int r = 0; r < 4; ++r) {
      float y = fmaxf(acc3[t][r] + b1, 0.f);
      lds_t[wave][swz(quad * 4 + r, t * 16 + row16, 128)] = f2bf(y);
    }
  }
  __syncthreads();

  // ---- layer e2: [16,64] @ [64,64]; e_out = relu(e + upd)
  f32x4 acc4[4];
#pragma unroll
  for (int t = 0; t < 4; ++t) acc4[t] = (f32x4)0.0f;
#pragma unroll
  for (int c = 0; c < 2; ++c) {
    short8 a = *(const short8*)&lds_t[wave][swz(row16, c * 32 + quad * 8, 128)];
    const short* bp = pWe2 + (size_t)(c * 4 + quad) * ED * 8 + row16 * 8;
#pragma unroll
    for (int t = 0; t < 4; ++t) {
      short8 b = *(const short8*)(bp + t * 16 * 8);
      acc4[t] = __builtin_amdgcn_mfma_f32_16x16x32_bf16(a, b, acc4[t], 0, 0, 0);
    }
  }
#pragma unroll
  for (int t = 0; t < 4; ++t) {
    float b2 = be2[t * 16 + row16];
#pragma unroll
    for (int r = 0; r < 4; ++r) {
      int erow = ebase + quad * 4 + r;
      int col = t * 16 + row16;
      float v = e[(size_t)erow * ED + col] + acc4[t][r] + b2;
      e_out[(size_t)erow * ED + col] = fmaxf(v, 0.f);
    }
  }
}

// Node kernel: h_out = relu(h + MLP([h, m_aggr, g_b])), h_att = h_out.Wha+bha,
// atomicAdd h_aggr[batch] += h_att*h_out
__global__ __launch_bounds__(256) void node_kernel(
    const float* __restrict__ h, const float* __restrict__ m_aggr,
    const float* __restrict__ g, const int* __restrict__ batch,
    const short* __restrict__ pWh1, const float* __restrict__ bh1,
    const short* __restrict__ pWh2, const float* __restrict__ bh2,
    const float* __restrict__ Wha, const float* __restrict__ bha,
    float* __restrict__ h_out, float* __restrict__ h_aggr) {
  __shared__ short lds_y[4][16 * 128];

  const int wave = threadIdx.x >> 6;
  const int lane = threadIdx.x & 63;
  const int row16 = lane & 15;
  const int quad = lane >> 4;
  const int nbase = blockIdx.x * 64 + wave * 16;

  int nA = nbase + row16;
  int nAc = nA < NN ? nA : NN - 1;
  int gbA = batch[nAc];
  const float* seg0 = h + (size_t)nAc * HD;
  const float* seg1 = m_aggr + (size_t)nAc * HID;
  const float* seg2 = g + (size_t)gbA * GD;

  f32x4 acc[8];
#pragma unroll
  for (int t = 0; t < 8; ++t) acc[t] = (f32x4)0.0f;
#pragma unroll
  for (int c = 0; c < 10; ++c) {
    const float* src; int off;
    if (c < 4)      { src = seg0; off = c * 32; }
    else if (c < 8) { src = seg1; off = (c - 4) * 32; }
    else            { src = seg2; off = (c - 8) * 32; }
    short8 a = load_a8(src + off + quad * 8);
    const short* bp = pWh1 + (size_t)(c * 4 + quad) * HD * 8 + row16 * 8;
#pragma unroll
    for (int t = 0; t < 8; ++t) {
      short8 b = *(const short8*)(bp + t * 16 * 8);
      acc[t] = __builtin_amdgcn_mfma_f32_16x16x32_bf16(a, b, acc[t], 0, 0, 0);
    }
  }
#pragma unroll
  for (int t = 0; t < 8; ++t) {
    float b1 = bh1[t * 16 + row16];
#pragma unroll
    for (int r = 0; r < 4; ++r) {
      float y = fmaxf(acc[t][r] + b1, 0.f);
      lds_y[wave][swz(quad * 4 + r, t * 16 + row16, 256)] = f2bf(y);
    }
  }
  __syncthreads();

  f32x4 acc2[8];
#pragma unroll
  for (int t = 0; t < 8; ++t) acc2[t] = (f32x4)0.0f;
#pragma unroll
  for (int c = 0; c < 4; ++c) {
    short8 a = *(const short8*)&lds_y[wave][swz(row16, c * 32 + quad * 8, 256)];
    const short* bp = pWh2 + (size_t)(c * 4 + quad) * HD * 8 + row16 * 8;
#pragma unroll
    for (int t = 0; t < 8; ++t) {
      short8 b = *(const short8*)(bp + t * 16 * 8);
      acc2[t] = __builtin_amdgcn_mfma_f32_16x16x32_bf16(a, b, acc2[t], 0, 0, 0);
    }
  }

  float hval[8][4];
  int nS[4];
#pragma unroll
  for (int r = 0; r < 4; ++r) nS[r] = nbase + quad * 4 + r;
#pragma unroll
  for (int t = 0; t < 8; ++t) {
    float b2 = bh2[t * 16 + row16];
#pragma unroll
    for (int r = 0; r < 4; ++r) {
      float v = 0.f;
      if (nS[r] < NN) {
        v = h[(size_t)nS[r] * HD + t * 16 + row16] + acc2[t][r] + b2;
        v = fmaxf(v, 0.f);
        h_out[(size_t)nS[r] * HD + t * 16 + row16] = v;
      }
      hval[t][r] = v;
    }
  }

  // h_att (linear, no activation)
  float part[4] = {0.f, 0.f, 0.f, 0.f};
#pragma unroll
  for (int t = 0; t < 8; ++t) {
    float w = Wha[t * 16 + row16];
#pragma unroll
    for (int r = 0; r < 4; ++r) part[r] += hval[t][r] * w;
  }
#pragma unroll
  for (int s = 1; s < 16; s <<= 1) {
#pragma unroll
    for (int r = 0; r < 4; ++r) part[r] += __shfl_xor(part[r], s, 64);
  }
  float bha0 = bha[0];
  int bS[4];
#pragma unroll
  for (int r = 0; r < 4; ++r) bS[r] = (nS[r] < NN) ? batch[nS[r]] : 0;
#pragma unroll
  for (int t = 0; t < 8; ++t)
#pragma unroll
    for (int r = 0; r < 4; ++r)
      if (nS[r] < NN)
        atomicAdd(&h_aggr[(size_t)bS[r] * HD + t * 16 + row16],
                  (part[r] + bha0) * hval[t][r]);
}

// Global kernel: one wave per graph row (scalar f32, tiny)
__global__ void g_kernel(const float* __restrict__ g, const float* __restrict__ h_aggr,
                         const float* __restrict__ Wg1, const float* __restrict__ bg1,
                         const float* __restrict__ Wg2, const float* __restrict__ bg2,
                         float* __restrict__ g_out) {
  __shared__ float cat[192];
  __shared__ float y1[64];
  int r = blockIdx.x;
  int t = threadIdx.x;  // 64 threads
  cat[t] = g[(size_t)r * GD + t];
  cat[64 + t] = h_aggr[(size_t)r * HD + t];
  cat[128 + t] = h_aggr[(size_t)r * HD + 64 + t];
  __syncthreads();
  float a = bg1[t];
  for (int k = 0; k < 192; ++k) a += cat[k] * Wg1[k * 64 + t];
  y1[t] = fmaxf(a, 0.f);
  __syncthreads();
  float b = bg2[t];
  for (int k = 0; k < 64; ++k) b += y1[k] * Wg2[k * 64 + t];
  float v = g[(size_t)r * GD + t] + b;
  g_out[(size_t)r * GD + t] = fmaxf(v, 0.f);
}

extern "C" void kernel_launch(void* const* d_in, const int* in_sizes, int n_in,
                              void* d_out, int out_size, void* d_ws, size_t ws_size,
                              hipStream_t stream) {
  const float* h = (const float*)d_in[0];
  const int* ei = (const int*)d_in[1];
  const float* e = (const float*)d_in[2];
  const float* g = (const float*)d_in[3];
  const int* batch = (const int*)d_in[4];
  const float* Wm1 = (const float*)d_in[5];
  const float* bm1 = (const float*)d_in[6];
  const float* Wm2 = (const float*)d_in[7];
  const float* bm2 = (const float*)d_in[8];
  const float* Wma = (const float*)d_in[9];
  const float* bma = (const float*)d_in[10];
  const float* We1 = (const float*)d_in[11];
  const float* be1 = (const float*)d_in[12];
  const float* We2 = (const float*)d_in[13];
  const float* be2 = (const float*)d_in[14];
  const float* Wh1 = (const float*)d_in[15];
  const float* bh1 = (const float*)d_in[16];
  const float* Wh2 = (const float*)d_in[17];
  const float* bh2 = (const float*)d_in[18];
  const float* Wha = (const float*)d_in[19];
  const float* bha = (const float*)d_in[20];
  const float* Wg1 = (const float*)d_in[21];
  const float* bg1 = (const float*)d_in[22];
  const float* Wg2 = (const float*)d_in[23];
  const float* bg2 = (const float*)d_in[24];

  float* out = (float*)d_out;
  float* h_out = out;
  float* e_out = out + (size_t)NN * HD;
  float* g_out = e_out + (size_t)NE * ED;

  char* ws = (char*)d_ws;
  float* m_aggr = (float*)ws;                       // NN*HID f32 = 25.6 MB
  float* h_aggr = (float*)(ws + 25600000);          // NG*HD f32 = 256 KB
  short* packed = (short*)(ws + 25862144);          // 135168 bf16
  short* pWm1 = packed;
  short* pWm2 = packed + 49152;
  short* pWe1 = packed + 65536;
  short* pWe2 = packed + 73728;
  short* pWh1 = packed + 77824;
  short* pWh2 = packed + 118784;

  hipMemsetAsync(m_aggr, 0, (size_t)NN * HID * 4, stream);
  hipMemsetAsync(h_aggr, 0, (size_t)NG * HD * 4, stream);

  pack_kernel<<<(135168 + 255) / 256, 256, 0, stream>>>(Wm1, Wm2, We1, We2, Wh1, Wh2, packed);

  edge_kernel<<<NE / 64, 256, 0, stream>>>(h, ei, e, g, batch,
                                           pWm1, bm1, pWm2, bm2, Wma, bma,
                                           pWe1, be1, pWe2, be2, e_out, m_aggr);

  node_kernel<<<(NN + 63) / 64, 256, 0, stream>>>(h, m_aggr, g, batch,
                                                  pWh1, bh1, pWh2, bh2, Wha, bha,
                                                  h_out, h_aggr);

  g_kernel<<<NG, 64, 0, stream>>>(g, h_aggr, Wg1, bg1, Wg2, bg2, g_out);
}

// Round 2
// 692.015 us; speedup vs baseline: 1.0910x; 1.0910x over previous
//
#include <hip/hip_runtime.h>
#include <hip/hip_bf16.h>

#define NN 50000
#define NE 800000
#define NG 512
#define HD 128
#define ED 64
#define GD 64
#define HID 128

typedef __attribute__((ext_vector_type(8))) short short8;
typedef __attribute__((ext_vector_type(4))) float f32x4;

__device__ __forceinline__ short f2bf(float f) {
  union { float f; unsigned u; } v; v.f = f;
  unsigned r = v.u + 0x7fffu + ((v.u >> 16) & 1u);
  return (short)(r >> 16);
}

__device__ __forceinline__ float bf2f(short s) {
  union { unsigned u; float f; } v;
  v.u = ((unsigned)(unsigned short)s) << 16;
  return v.f;
}

__device__ __forceinline__ short8 load_a8(const float* p) {
  const f32x4* q = (const f32x4*)p;
  f32x4 x0 = q[0], x1 = q[1];
  short8 r;
  r[0]=f2bf(x0[0]); r[1]=f2bf(x0[1]); r[2]=f2bf(x0[2]); r[3]=f2bf(x0[3]);
  r[4]=f2bf(x1[0]); r[5]=f2bf(x1[1]); r[6]=f2bf(x1[2]); r[7]=f2bf(x1[3]);
  return r;
}

// swizzled LDS index (in shorts). rowBytes = row stride in bytes.
__device__ __forceinline__ int swz(int row, int col, int rowBytes) {
  int b = row * rowBytes + col * 2;
  b ^= (row & 7) << 4;
  return b >> 1;
}

// Pack f32 weight W[K][Ncol] -> bf16 Wp[(k>>3)*Ncol*8 + n*8 + (k&7)]
__global__ void pack_kernel(const float* __restrict__ Wm1, const float* __restrict__ Wm2,
                            const float* __restrict__ We1, const float* __restrict__ We2,
                            const float* __restrict__ Wh1, const float* __restrict__ Wh2,
                            short* __restrict__ out) {
  int gid = blockIdx.x * 256 + threadIdx.x;
  if (gid >= 135168) return;
  const float* W; int Ncol, base, idx;
  if (gid < 49152)       { W = Wm1; Ncol = 128; base = 0;      idx = gid; }
  else if (gid < 65536)  { W = Wm2; Ncol = 128; base = 49152;  idx = gid - 49152; }
  else if (gid < 73728)  { W = We1; Ncol = 64;  base = 65536;  idx = gid - 65536; }
  else if (gid < 77824)  { W = We2; Ncol = 64;  base = 73728;  idx = gid - 73728; }
  else if (gid < 118784) { W = Wh1; Ncol = 128; base = 77824;  idx = gid - 77824; }
  else                   { W = Wh2; Ncol = 128; base = 118784; idx = gid - 118784; }
  int k = idx / Ncol, n = idx % Ncol;
  out[base + (k >> 3) * Ncol * 8 + n * 8 + (k & 7)] = f2bf(W[idx]);
}

// ---- CSR build ----
__global__ void count_kernel(const int* __restrict__ ei, int* __restrict__ deg) {
  int i = blockIdx.x * 256 + threadIdx.x;
  if (i < NE) atomicAdd(&deg[ei[NE + i]], 1);
}

// Single-block exclusive scan over deg[NN], in place -> offsets.
__global__ __launch_bounds__(1024) void scan_kernel(int* __restrict__ deg) {
  __shared__ int psum[1024];
  const int CH = 49;  // 1024*49 >= 50000
  int t = threadIdx.x;
  int lo = t * CH, hi = lo + CH; if (hi > NN) hi = NN; if (lo > NN) lo = NN;
  int s = 0;
  for (int i = lo; i < hi; ++i) s += deg[i];
  psum[t] = s;
  __syncthreads();
  for (int d = 1; d < 1024; d <<= 1) {
    int v = (t >= d) ? psum[t - d] : 0;
    __syncthreads();
    psum[t] += v;
    __syncthreads();
  }
  int run = (t == 0) ? 0 : psum[t - 1];
  for (int i = lo; i < hi; ++i) { int v = deg[i]; deg[i] = run; run += v; }
}

__global__ void scatter_kernel(const int* __restrict__ ei, int* __restrict__ off,
                               int* __restrict__ elist) {
  int i = blockIdx.x * 256 + threadIdx.x;
  if (i < NE) {
    int d = ei[NE + i];
    int p = atomicAdd(&off[d], 1);
    elist[p] = i;
  }
}

// Edge kernel, dst-sorted order: 64 edges/block, 4 waves x 16 rows.
// Aggregation via in-LDS segmented scan; atomics only at block boundaries.
__global__ __launch_bounds__(256) void edge_kernel(
    const float* __restrict__ h, const int* __restrict__ ei,
    const float* __restrict__ e, const float* __restrict__ g,
    const int* __restrict__ batch, const int* __restrict__ elist,
    const short* __restrict__ pWm1, const float* __restrict__ bm1,
    const short* __restrict__ pWm2, const float* __restrict__ bm2,
    const float* __restrict__ Wma, const float* __restrict__ bma,
    const short* __restrict__ pWe1, const float* __restrict__ be1,
    const short* __restrict__ pWe2, const float* __restrict__ be2,
    float* __restrict__ e_out, float* __restrict__ m_aggr) {
  __shared__ short lds_m[4][16 * 128];
  __shared__ short lds_t[4][16 * 64];
  __shared__ short lds_w[64 * 132];
  __shared__ int sdst[64];

  const int wave = threadIdx.x >> 6;
  const int lane = threadIdx.x & 63;
  const int row16 = lane & 15;
  const int quad = lane >> 4;
  const int pbase = blockIdx.x * 64 + wave * 16;

  const int eidA = elist[pbase + row16];
  const int srcA = ei[eidA];
  const int dstA = ei[NE + eidA];
  const int gbA = batch[dstA];
  if (quad == 0) sdst[wave * 16 + row16] = dstA;

  const float* seg0 = h + (size_t)srcA * HD;
  const float* seg1 = h + (size_t)dstA * HD;
  const float* seg2 = e + (size_t)eidA * ED;
  const float* seg3 = g + (size_t)gbA * GD;

  // ---- layer m1: [16,384] @ [384,128]
  f32x4 acc[8];
#pragma unroll
  for (int t = 0; t < 8; ++t) acc[t] = (f32x4)0.0f;
#pragma unroll
  for (int c = 0; c < 12; ++c) {
    const float* src; int off;
    if (c < 4)       { src = seg0; off = c * 32; }
    else if (c < 8)  { src = seg1; off = (c - 4) * 32; }
    else if (c < 10) { src = seg2; off = (c - 8) * 32; }
    else             { src = seg3; off = (c - 10) * 32; }
    short8 a = load_a8(src + off + quad * 8);
    const short* bp = pWm1 + (size_t)(c * 4 + quad) * HID * 8 + row16 * 8;
#pragma unroll
    for (int t = 0; t < 8; ++t) {
      short8 b = *(const short8*)(bp + t * 16 * 8);
      acc[t] = __builtin_amdgcn_mfma_f32_16x16x32_bf16(a, b, acc[t], 0, 0, 0);
    }
  }
#pragma unroll
  for (int t = 0; t < 8; ++t) {
    float b1 = bm1[t * 16 + row16];
#pragma unroll
    for (int r = 0; r < 4; ++r) {
      float y = fmaxf(acc[t][r] + b1, 0.f);
      lds_m[wave][swz(quad * 4 + r, t * 16 + row16, 256)] = f2bf(y);
    }
  }

  // ---- layer m2: [16,128] @ [128,128]  (per-wave LDS tile, no barrier needed)
  f32x4 acc2[8];
#pragma unroll
  for (int t = 0; t < 8; ++t) acc2[t] = (f32x4)0.0f;
#pragma unroll
  for (int c = 0; c < 4; ++c) {
    short8 a = *(const short8*)&lds_m[wave][swz(row16, c * 32 + quad * 8, 256)];
    const short* bp = pWm2 + (size_t)(c * 4 + quad) * HID * 8 + row16 * 8;
#pragma unroll
    for (int t = 0; t < 8; ++t) {
      short8 b = *(const short8*)(bp + t * 16 * 8);
      acc2[t] = __builtin_amdgcn_mfma_f32_16x16x32_bf16(a, b, acc2[t], 0, 0, 0);
    }
  }

  float mval[8][4];
#pragma unroll
  for (int t = 0; t < 8; ++t) {
    float b2 = bm2[t * 16 + row16];
#pragma unroll
    for (int r = 0; r < 4; ++r) {
      float y = fmaxf(acc2[t][r] + b2, 0.f);
      mval[t][r] = y;
      lds_m[wave][swz(quad * 4 + r, t * 16 + row16, 256)] = f2bf(y);
    }
  }

  // ---- m_att = sigmoid(m . Wma + bma)
  float part[4] = {0.f, 0.f, 0.f, 0.f};
#pragma unroll
  for (int t = 0; t < 8; ++t) {
    float w = Wma[t * 16 + row16];
#pragma unroll
    for (int r = 0; r < 4; ++r) part[r] += mval[t][r] * w;
  }
#pragma unroll
  for (int s = 1; s < 16; s <<= 1) {
#pragma unroll
    for (int r = 0; r < 4; ++r) part[r] += __shfl_xor(part[r], s, 64);
  }
  float bma0 = bma[0];
  float attv[4];
#pragma unroll
  for (int r = 0; r < 4; ++r) attv[r] = 1.f / (1.f + __expf(-(part[r] + bma0)));

  // ---- weighted message -> LDS for segmented reduction
#pragma unroll
  for (int t = 0; t < 8; ++t)
#pragma unroll
    for (int r = 0; r < 4; ++r)
      lds_w[(wave * 16 + quad * 4 + r) * 132 + t * 16 + row16] = f2bf(attv[r] * mval[t][r]);

  __syncthreads();

  // ---- segmented flush: 128 threads, one column each, scan 64 rows
  if (threadIdx.x < 128) {
    int col = threadIdx.x;
    int cur = sdst[0];
    float sum = 0.f;
    int segs = 0;
#pragma unroll 1
    for (int r = 0; r < 64; ++r) {
      int d = sdst[r];
      float v = bf2f(lds_w[r * 132 + col]);
      if (d != cur) {
        if (segs == 0) atomicAdd(&m_aggr[(size_t)cur * HID + col], sum);
        else m_aggr[(size_t)cur * HID + col] = sum;
        cur = d; sum = v; segs = r;
      } else {
        sum += v;
      }
    }
    atomicAdd(&m_aggr[(size_t)cur * HID + col], sum);  // touches row 63
  }

  // ---- layer e1: [16,128] @ [128,64]
  f32x4 acc3[4];
#pragma unroll
  for (int t = 0; t < 4; ++t) acc3[t] = (f32x4)0.0f;
#pragma unroll
  for (int c = 0; c < 4; ++c) {
    short8 a = *(const short8*)&lds_m[wave][swz(row16, c * 32 + quad * 8, 256)];
    const short* bp = pWe1 + (size_t)(c * 4 + quad) * ED * 8 + row16 * 8;
#pragma unroll
    for (int t = 0; t < 4; ++t) {
      short8 b = *(const short8*)(bp + t * 16 * 8);
      acc3[t] = __builtin_amdgcn_mfma_f32_16x16x32_bf16(a, b, acc3[t], 0, 0, 0);
    }
  }
#pragma unroll
  for (int t = 0; t < 4; ++t) {
    float b1 = be1[t * 16 + row16];
#pragma unroll
    for (int r = 0; r < 4; ++r) {
      float y = fmaxf(acc3[t][r] + b1, 0.f);
      lds_t[wave][swz(quad * 4 + r, t * 16 + row16, 128)] = f2bf(y);
    }
  }

  // ---- layer e2: [16,64] @ [64,64]; e_out = relu(e + upd), scattered rows
  f32x4 acc4[4];
#pragma unroll
  for (int t = 0; t < 4; ++t) acc4[t] = (f32x4)0.0f;
#pragma unroll
  for (int c = 0; c < 2; ++c) {
    short8 a = *(const short8*)&lds_t[wave][swz(row16, c * 32 + quad * 8, 128)];
    const short* bp = pWe2 + (size_t)(c * 4 + quad) * ED * 8 + row16 * 8;
#pragma unroll
    for (int t = 0; t < 4; ++t) {
      short8 b = *(const short8*)(bp + t * 16 * 8);
      acc4[t] = __builtin_amdgcn_mfma_f32_16x16x32_bf16(a, b, acc4[t], 0, 0, 0);
    }
  }
  int eidS[4];
#pragma unroll
  for (int r = 0; r < 4; ++r) eidS[r] = elist[blockIdx.x * 64 + wave * 16 + quad * 4 + r];
#pragma unroll
  for (int t = 0; t < 4; ++t) {
    float b2 = be2[t * 16 + row16];
#pragma unroll
    for (int r = 0; r < 4; ++r) {
      int col = t * 16 + row16;
      float v = e[(size_t)eidS[r] * ED + col] + acc4[t][r] + b2;
      e_out[(size_t)eidS[r] * ED + col] = fmaxf(v, 0.f);
    }
  }
}

// Node kernel: batch is sorted -> segmented flush for h_aggr too.
__global__ __launch_bounds__(256) void node_kernel(
    const float* __restrict__ h, const float* __restrict__ m_aggr,
    const float* __restrict__ g, const int* __restrict__ batch,
    const short* __restrict__ pWh1, const float* __restrict__ bh1,
    const short* __restrict__ pWh2, const float* __restrict__ bh2,
    const float* __restrict__ Wha, const float* __restrict__ bha,
    float* __restrict__ h_out, float* __restrict__ h_aggr) {
  __shared__ short lds_y[4][16 * 128];
  __shared__ short lds_w2[64 * 132];
  __shared__ int sbat[64];

  const int wave = threadIdx.x >> 6;
  const int lane = threadIdx.x & 63;
  const int row16 = lane & 15;
  const int quad = lane >> 4;
  const int nbase = blockIdx.x * 64 + wave * 16;

  int nA = nbase + row16;
  int nAc = nA < NN ? nA : NN - 1;
  int gbA = batch[nAc];
  if (quad == 0) sbat[wave * 16 + row16] = (nA < NN) ? gbA : -1;
  const float* seg0 = h + (size_t)nAc * HD;
  const float* seg1 = m_aggr + (size_t)nAc * HID;
  const float* seg2 = g + (size_t)gbA * GD;

  f32x4 acc[8];
#pragma unroll
  for (int t = 0; t < 8; ++t) acc[t] = (f32x4)0.0f;
#pragma unroll
  for (int c = 0; c < 10; ++c) {
    const float* src; int off;
    if (c < 4)      { src = seg0; off = c * 32; }
    else if (c < 8) { src = seg1; off = (c - 4) * 32; }
    else            { src = seg2; off = (c - 8) * 32; }
    short8 a = load_a8(src + off + quad * 8);
    const short* bp = pWh1 + (size_t)(c * 4 + quad) * HD * 8 + row16 * 8;
#pragma unroll
    for (int t = 0; t < 8; ++t) {
      short8 b = *(const short8*)(bp + t * 16 * 8);
      acc[t] = __builtin_amdgcn_mfma_f32_16x16x32_bf16(a, b, acc[t], 0, 0, 0);
    }
  }
#pragma unroll
  for (int t = 0; t < 8; ++t) {
    float b1 = bh1[t * 16 + row16];
#pragma unroll
    for (int r = 0; r < 4; ++r) {
      float y = fmaxf(acc[t][r] + b1, 0.f);
      lds_y[wave][swz(quad * 4 + r, t * 16 + row16, 256)] = f2bf(y);
    }
  }

  f32x4 acc2[8];
#pragma unroll
  for (int t = 0; t < 8; ++t) acc2[t] = (f32x4)0.0f;
#pragma unroll
  for (int c = 0; c < 4; ++c) {
    short8 a = *(const short8*)&lds_y[wave][swz(row16, c * 32 + quad * 8, 256)];
    const short* bp = pWh2 + (size_t)(c * 4 + quad) * HD * 8 + row16 * 8;
#pragma unroll
    for (int t = 0; t < 8; ++t) {
      short8 b = *(const short8*)(bp + t * 16 * 8);
      acc2[t] = __builtin_amdgcn_mfma_f32_16x16x32_bf16(a, b, acc2[t], 0, 0, 0);
    }
  }

  float hval[8][4];
  int nS[4];
#pragma unroll
  for (int r = 0; r < 4; ++r) nS[r] = nbase + quad * 4 + r;
#pragma unroll
  for (int t = 0; t < 8; ++t) {
    float b2 = bh2[t * 16 + row16];
#pragma unroll
    for (int r = 0; r < 4; ++r) {
      float v = 0.f;
      if (nS[r] < NN) {
        v = h[(size_t)nS[r] * HD + t * 16 + row16] + acc2[t][r] + b2;
        v = fmaxf(v, 0.f);
        h_out[(size_t)nS[r] * HD + t * 16 + row16] = v;
      }
      hval[t][r] = v;
    }
  }

  // h_att (linear)
  float part[4] = {0.f, 0.f, 0.f, 0.f};
#pragma unroll
  for (int t = 0; t < 8; ++t) {
    float w = Wha[t * 16 + row16];
#pragma unroll
    for (int r = 0; r < 4; ++r) part[r] += hval[t][r] * w;
  }
#pragma unroll
  for (int s = 1; s < 16; s <<= 1) {
#pragma unroll
    for (int r = 0; r < 4; ++r) part[r] += __shfl_xor(part[r], s, 64);
  }
  float bha0 = bha[0];
#pragma unroll
  for (int t = 0; t < 8; ++t)
#pragma unroll
    for (int r = 0; r < 4; ++r)
      lds_w2[(wave * 16 + quad * 4 + r) * 132 + t * 16 + row16] =
          f2bf((part[r] + bha0) * hval[t][r]);

  __syncthreads();

  if (threadIdx.x < 128) {
    int col = threadIdx.x;
    int cur = sbat[0];
    float sum = 0.f;
    int segs = 0;
#pragma unroll 1
    for (int r = 0; r < 64; ++r) {
      int d = sbat[r];
      float v = bf2f(lds_w2[r * 132 + col]);
      if (d != cur) {
        if (cur >= 0) {
          if (segs == 0) atomicAdd(&h_aggr[(size_t)cur * HD + col], sum);
          else h_aggr[(size_t)cur * HD + col] = sum;
        }
        cur = d; sum = v; segs = r;
      } else {
        sum += v;
      }
    }
    if (cur >= 0) atomicAdd(&h_aggr[(size_t)cur * HD + col], sum);
  }
}

// Global kernel: one wave per graph row
__global__ void g_kernel(const float* __restrict__ g, const float* __restrict__ h_aggr,
                         const float* __restrict__ Wg1, const float* __restrict__ bg1,
                         const float* __restrict__ Wg2, const float* __restrict__ bg2,
                         float* __restrict__ g_out) {
  __shared__ float cat[192];
  __shared__ float y1[64];
  int r = blockIdx.x;
  int t = threadIdx.x;  // 64 threads
  cat[t] = g[(size_t)r * GD + t];
  cat[64 + t] = h_aggr[(size_t)r * HD + t];
  cat[128 + t] = h_aggr[(size_t)r * HD + 64 + t];
  __syncthreads();
  float a = bg1[t];
  for (int k = 0; k < 192; ++k) a += cat[k] * Wg1[k * 64 + t];
  y1[t] = fmaxf(a, 0.f);
  __syncthreads();
  float b = bg2[t];
  for (int k = 0; k < 64; ++k) b += y1[k] * Wg2[k * 64 + t];
  float v = g[(size_t)r * GD + t] + b;
  g_out[(size_t)r * GD + t] = fmaxf(v, 0.f);
}

extern "C" void kernel_launch(void* const* d_in, const int* in_sizes, int n_in,
                              void* d_out, int out_size, void* d_ws, size_t ws_size,
                              hipStream_t stream) {
  const float* h = (const float*)d_in[0];
  const int* ei = (const int*)d_in[1];
  const float* e = (const float*)d_in[2];
  const float* g = (const float*)d_in[3];
  const int* batch = (const int*)d_in[4];
  const float* Wm1 = (const float*)d_in[5];
  const float* bm1 = (const float*)d_in[6];
  const float* Wm2 = (const float*)d_in[7];
  const float* bm2 = (const float*)d_in[8];
  const float* Wma = (const float*)d_in[9];
  const float* bma = (const float*)d_in[10];
  const float* We1 = (const float*)d_in[11];
  const float* be1 = (const float*)d_in[12];
  const float* We2 = (const float*)d_in[13];
  const float* be2 = (const float*)d_in[14];
  const float* Wh1 = (const float*)d_in[15];
  const float* bh1 = (const float*)d_in[16];
  const float* Wh2 = (const float*)d_in[17];
  const float* bh2 = (const float*)d_in[18];
  const float* Wha = (const float*)d_in[19];
  const float* bha = (const float*)d_in[20];
  const float* Wg1 = (const float*)d_in[21];
  const float* bg1 = (const float*)d_in[22];
  const float* Wg2 = (const float*)d_in[23];
  const float* bg2 = (const float*)d_in[24];

  float* out = (float*)d_out;
  float* h_out = out;
  float* e_out = out + (size_t)NN * HD;
  float* g_out = e_out + (size_t)NE * ED;

  char* ws = (char*)d_ws;
  float* m_aggr = (float*)ws;                     // 25,600,000 B
  float* h_aggr = (float*)(ws + 25600000);        // 262,144 B
  short* packed = (short*)(ws + 25862144);        // 270,336 B
  int* deg      = (int*)(ws + 26132480);          // 200,000 B
  int* elist    = (int*)(ws + 26332480);          // 3,200,000 B
  short* pWm1 = packed;
  short* pWm2 = packed + 49152;
  short* pWe1 = packed + 65536;
  short* pWe2 = packed + 73728;
  short* pWh1 = packed + 77824;
  short* pWh2 = packed + 118784;

  hipMemsetAsync(m_aggr, 0, (size_t)NN * HID * 4, stream);
  hipMemsetAsync(h_aggr, 0, (size_t)NG * HD * 4, stream);
  hipMemsetAsync(deg, 0, (size_t)NN * 4, stream);

  pack_kernel<<<(135168 + 255) / 256, 256, 0, stream>>>(Wm1, Wm2, We1, We2, Wh1, Wh2, packed);
  count_kernel<<<(NE + 255) / 256, 256, 0, stream>>>(ei, deg);
  scan_kernel<<<1, 1024, 0, stream>>>(deg);
  scatter_kernel<<<(NE + 255) / 256, 256, 0, stream>>>(ei, deg, elist);

  edge_kernel<<<NE / 64, 256, 0, stream>>>(h, ei, e, g, batch, elist,
                                           pWm1, bm1, pWm2, bm2, Wma, bma,
                                           pWe1, be1, pWe2, be2, e_out, m_aggr);

  node_kernel<<<(NN + 63) / 64, 256, 0, stream>>>(h, m_aggr, g, batch,
                                                  pWh1, bh1, pWh2, bh2, Wha, bha,
                                                  h_out, h_aggr);

  g_kernel<<<NG, 64, 0, stream>>>(g, h_aggr, Wg1, bg1, Wg2, bg2, g_out);
}